// Round 7
// baseline (239.986 us; speedup 1.0000x reference)
//
#include <hip/hip_runtime.h>
#include <hip/hip_bf16.h>
#include <math.h>

#define N_ROWS 8192
#define DIM    1024
#define NB     (N_ROWS / 128)       // 64 tiles per side
#define NT     (NB * (NB + 1) / 2)  // 2080 triangular blocks

typedef __bf16 bf16_t;
typedef __bf16 bf16x4 __attribute__((ext_vector_type(4)));
typedef __bf16 bf16x8 __attribute__((ext_vector_type(8)));
typedef float  f32x4  __attribute__((ext_vector_type(4)));

// global -> LDS direct copy, 16B per lane; LDS dest must be wave-uniform
#define GLOAD_LDS(g, s) __builtin_amdgcn_global_load_lds(                      \
    (const __attribute__((address_space(1))) void*)(g),                        \
    (__attribute__((address_space(3))) void*)(s), 16, 0, 0)

// Order-preserving float -> uint map (atomicMax on floats incl. negatives)
__device__ __forceinline__ unsigned fmap(float f) {
    unsigned u = __float_as_uint(f);
    return (u & 0x80000000u) ? ~u : (u | 0x80000000u);
}
__device__ __forceinline__ float funmap(unsigned u) {
    return (u & 0x80000000u) ? __uint_as_float(u ^ 0x80000000u)
                             : __uint_as_float(~u);
}

// ---------------------------------------------------------------------------
// Kernel 1: L2-normalize rows. One WAVE per row. Also zero row_max + counter.
// ---------------------------------------------------------------------------
__global__ __launch_bounds__(256) void k_normalize(const float* __restrict__ x,
                                                   bf16_t* __restrict__ xb,
                                                   unsigned* __restrict__ row_max,
                                                   unsigned* __restrict__ counter) {
    const int tid = threadIdx.x;
    const int l   = tid & 63;
    const int row = blockIdx.x * 4 + (tid >> 6);
    const float4* xr = reinterpret_cast<const float4*>(x + (size_t)row * DIM);

    float4 v[4];
    float ss = 0.0f;
    #pragma unroll
    for (int c = 0; c < 4; ++c) {
        v[c] = xr[l + c * 64];
        ss += v[c].x * v[c].x + v[c].y * v[c].y + v[c].z * v[c].z + v[c].w * v[c].w;
    }
    #pragma unroll
    for (int m = 32; m >= 1; m >>= 1) ss += __shfl_xor(ss, m);
    const float scale = 1.0f / fmaxf(sqrtf(ss), 1e-12f);

    bf16x4* xo = reinterpret_cast<bf16x4*>(xb + (size_t)row * DIM);
    #pragma unroll
    for (int c = 0; c < 4; ++c) {
        bf16x4 o;
        o[0] = (bf16_t)(v[c].x * scale);
        o[1] = (bf16_t)(v[c].y * scale);
        o[2] = (bf16_t)(v[c].z * scale);
        o[3] = (bf16_t)(v[c].w * scale);
        xo[l + c * 64] = o;
    }

    if (blockIdx.x < N_ROWS / 256)
        row_max[blockIdx.x * 256 + tid] = 0u;   // mapped surrogate for -inf
    if (blockIdx.x == 0 && tid == 0) counter[0] = 0u;
}

// ---------------------------------------------------------------------------
// Kernel 2: row/col-max of sim = Xb*Xb^T over upper-triangular 128x128 tiles.
// Round-4 structure + STATIC 2-phase prefetch (fixed buffer symbols, no
// runtime indexing): STAGE(next buf) issued before COMPUTE(cur buf), ONE
// __syncthreads per BK=32 K-step. [128][32] tiles (64B rows — bank-benign).
// 2x2 waves, 64x64 out/wave. C/D: col = lane&15, row = (lane>>4)*4 + reg.
// Last block (atomic counter) computes the final loss — no k_finish launch.
// ---------------------------------------------------------------------------
__global__ __launch_bounds__(256) void k_simmax(const bf16_t* __restrict__ xb,
                                                unsigned* __restrict__ row_max,
                                                unsigned* __restrict__ counter,
                                                float* __restrict__ out) {
    __shared__ bf16_t smA0[128 * 32], smA1[128 * 32];
    __shared__ bf16_t smB0[128 * 32], smB1[128 * 32];
    const int tid = threadIdx.x;
    const int w  = tid >> 6;
    const int l  = tid & 63;
    const int lr = l & 15;
    const int lk = (l >> 4) * 8;
    const int wr = w >> 1, wc = w & 1;

    // linear block id -> upper-triangular (bi, bj), bi <= bj
    int t = blockIdx.x;
    #define TOFF(b) ((b) * NB - ((b) * ((b) - 1)) / 2)
    int bi = (int)((float)(2 * NB + 1 -
                sqrtf((float)((2 * NB + 1) * (2 * NB + 1) - 8 * t))) * 0.5f);
    if (bi < 0) bi = 0;
    if (bi > NB - 1) bi = NB - 1;
    while (TOFF(bi + 1) <= t) ++bi;
    while (TOFF(bi) > t) --bi;
    const int bj = bi + (t - TOFF(bi));
    const int i0 = bi * 128, j0 = bj * 128;

    // staging: thread tid covers row tid>>2, 8-elem chunk tid&3 of a
    // row-major [128][32] half-tile; gload_lds lands at wbase + lane*8 elems.
    const bf16_t* gA = xb + (size_t)(i0 + (tid >> 2)) * DIM + (tid & 3) * 8;
    const bf16_t* gB = xb + (size_t)(j0 + (tid >> 2)) * DIM + (tid & 3) * 8;
    const int wbase = (tid & ~63) * 8;      // wave-uniform LDS elem offset

    #define STAGE(sa, sb, kk) do {                                             \
        GLOAD_LDS(gA + (kk),            (sa) + wbase);                         \
        GLOAD_LDS(gA + 64 * DIM + (kk), (sa) + 2048 + wbase);                  \
        GLOAD_LDS(gB + (kk),            (sb) + wbase);                         \
        GLOAD_LDS(gB + 64 * DIM + (kk), (sb) + 2048 + wbase);                  \
    } while (0)

    f32x4 acc[4][4] = {};
    const int fa = (wr * 64 + lr) * 32 + lk;   // frag base offsets in a tile
    const int fb = (wc * 64 + lr) * 32 + lk;

    #define COMPUTE(sa, sb) do {                                               \
        bf16x8 af[4], bfr[4];                                                  \
        _Pragma("unroll")                                                      \
        for (int m = 0; m < 4; ++m) af[m]  = *(const bf16x8*)((sa) + fa + m * 512); \
        _Pragma("unroll")                                                      \
        for (int n = 0; n < 4; ++n) bfr[n] = *(const bf16x8*)((sb) + fb + n * 512); \
        _Pragma("unroll")                                                      \
        for (int m = 0; m < 4; ++m)                                            \
            _Pragma("unroll")                                                  \
            for (int n = 0; n < 4; ++n)                                        \
                acc[m][n] = __builtin_amdgcn_mfma_f32_16x16x32_bf16(           \
                                af[m], bfr[n], acc[m][n], 0, 0, 0);            \
    } while (0)

    STAGE(smA0, smB0, 0);
    __syncthreads();
    for (int k = 0; k < DIM - 64; k += 64) {
        STAGE(smA1, smB1, k + 32);         // prefetch overlaps compute
        COMPUTE(smA0, smB0);
        __syncthreads();
        STAGE(smA0, smB0, k + 64);
        COMPUTE(smA1, smB1);
        __syncthreads();
    }
    {   // tail pair: k = DIM-64
        STAGE(smA1, smB1, DIM - 32);
        COMPUTE(smA0, smB0);
        __syncthreads();
        COMPUTE(smA1, smB1);
    }

    // Epilogue. Row-maxes for this wave's 64 rows (reduce over lr group).
    #pragma unroll
    for (int m = 0; m < 4; ++m) {
        #pragma unroll
        for (int j = 0; j < 4; ++j) {
            const int rowg = i0 + wr * 64 + m * 16 + (l >> 4) * 4 + j;
            float rm = -3.0e38f;
            #pragma unroll
            for (int n = 0; n < 4; ++n) {
                float s = acc[m][n][j];
                if (rowg == (j0 + wc * 64 + n * 16 + lr)) s = -3.0e38f;
                rm = fmaxf(rm, s);
            }
            #pragma unroll
            for (int mask = 1; mask < 16; mask <<= 1)
                rm = fmaxf(rm, __shfl_xor(rm, mask));
            if (lr == 0)
                atomicMax(&row_max[rowg], fmap(fminf(rm, 1.0f)));
        }
    }
    // Col-maxes feed the symmetric rows (off-diagonal blocks only).
    if (bi != bj) {
        #pragma unroll
        for (int n = 0; n < 4; ++n) {
            const int colg = j0 + wc * 64 + n * 16 + lr;
            float cm = -3.0e38f;
            #pragma unroll
            for (int m = 0; m < 4; ++m)
                #pragma unroll
                for (int j = 0; j < 4; ++j)
                    cm = fmaxf(cm, acc[m][n][j]);
            cm = fmaxf(cm, __shfl_xor(cm, 16));
            cm = fmaxf(cm, __shfl_xor(cm, 32));
            if (l < 16)
                atomicMax(&row_max[colg], fmap(fminf(cm, 1.0f)));
        }
    }

    // Last-block finish: loss = -mean(log(sqrt(2-2*min(max,1)+1e-4)+1e-8)).
    __syncthreads();                      // all this block's atomics issued
    __shared__ unsigned slast;
    if (tid == 0) {
        __threadfence();                  // order our maxes before the count
        slast = (atomicAdd(counter, 1u) == NT - 1) ? 1u : 0u;
    }
    __syncthreads();
    if (slast) {
        float sum = 0.0f;
        for (int i = tid; i < N_ROWS; i += 256) {
            unsigned u = atomicMax(&row_max[i], 0u);   // coherent read
            float sim = fminf(funmap(u), 1.0f);
            float dist = sqrtf(2.0f - 2.0f * sim + 1e-4f);
            sum += logf(dist + 1e-8f);
        }
        #pragma unroll
        for (int m = 32; m >= 1; m >>= 1) sum += __shfl_xor(sum, m);
        __shared__ float wss[4];
        if ((tid & 63) == 0) wss[tid >> 6] = sum;
        __syncthreads();
        if (tid == 0)
            out[0] = -(wss[0] + wss[1] + wss[2] + wss[3]) / (float)N_ROWS;
    }
}

// ---------------------------------------------------------------------------
extern "C" void kernel_launch(void* const* d_in, const int* in_sizes, int n_in,
                              void* d_out, int out_size, void* d_ws, size_t ws_size,
                              hipStream_t stream) {
    const float* x = (const float*)d_in[0];
    bf16_t* xb = (bf16_t*)d_ws;                                   // 16 MiB
    unsigned* row_max = (unsigned*)((char*)d_ws +
                         (size_t)N_ROWS * DIM * sizeof(bf16_t));  // +32 KiB
    unsigned* counter = row_max + N_ROWS;
    float* out = (float*)d_out;

    k_normalize<<<N_ROWS / 4, 256, 0, stream>>>(x, xb, row_max, counter);
    k_simmax<<<NT, 256, 0, stream>>>(xb, row_max, counter, out);
}

// Round 8
// 178.115 us; speedup vs baseline: 1.3474x; 1.3474x over previous
//
#include <hip/hip_runtime.h>
#include <hip/hip_bf16.h>
#include <math.h>

#define N_ROWS 8192
#define DIM    1024
#define NB     (N_ROWS / 128)       // 64 tiles per side
#define NT     (NB * (NB + 1) / 2)  // 2080 triangular blocks (2080 % 8 == 0)

typedef __bf16 bf16_t;
typedef __bf16 bf16x4 __attribute__((ext_vector_type(4)));
typedef __bf16 bf16x8 __attribute__((ext_vector_type(8)));
typedef float  f32x4  __attribute__((ext_vector_type(4)));

// global -> LDS direct copy, 16B per lane; LDS dest must be wave-uniform
#define GLOAD_LDS(g, s) __builtin_amdgcn_global_load_lds(                      \
    (const __attribute__((address_space(1))) void*)(g),                        \
    (__attribute__((address_space(3))) void*)(s), 16, 0, 0)

// Order-preserving float -> uint map (atomicMax on floats incl. negatives)
__device__ __forceinline__ unsigned fmap(float f) {
    unsigned u = __float_as_uint(f);
    return (u & 0x80000000u) ? ~u : (u | 0x80000000u);
}
__device__ __forceinline__ float funmap(unsigned u) {
    return (u & 0x80000000u) ? __uint_as_float(u ^ 0x80000000u)
                             : __uint_as_float(~u);
}

// ---------------------------------------------------------------------------
// Kernel 1: L2-normalize rows. One WAVE per row (no block reduce, no LDS).
// ---------------------------------------------------------------------------
__global__ __launch_bounds__(256) void k_normalize(const float* __restrict__ x,
                                                   bf16_t* __restrict__ xb,
                                                   unsigned* __restrict__ row_max) {
    const int tid = threadIdx.x;
    const int l   = tid & 63;
    const int row = blockIdx.x * 4 + (tid >> 6);
    const float4* xr = reinterpret_cast<const float4*>(x + (size_t)row * DIM);

    float4 v[4];
    float ss = 0.0f;
    #pragma unroll
    for (int c = 0; c < 4; ++c) {
        v[c] = xr[l + c * 64];
        ss += v[c].x * v[c].x + v[c].y * v[c].y + v[c].z * v[c].z + v[c].w * v[c].w;
    }
    #pragma unroll
    for (int m = 32; m >= 1; m >>= 1) ss += __shfl_xor(ss, m);
    const float scale = 1.0f / fmaxf(sqrtf(ss), 1e-12f);

    bf16x4* xo = reinterpret_cast<bf16x4*>(xb + (size_t)row * DIM);
    #pragma unroll
    for (int c = 0; c < 4; ++c) {
        bf16x4 o;
        o[0] = (bf16_t)(v[c].x * scale);
        o[1] = (bf16_t)(v[c].y * scale);
        o[2] = (bf16_t)(v[c].z * scale);
        o[3] = (bf16_t)(v[c].w * scale);
        xo[l + c * 64] = o;
    }

    if (blockIdx.x < N_ROWS / 256)
        row_max[blockIdx.x * 256 + tid] = 0u;   // mapped surrogate for -inf
}

// ---------------------------------------------------------------------------
// Kernel 2: row/col-max of sim = Xb*Xb^T over upper-triangular 128x128 tiles.
// Round-4 proven structure: single-buffer [128][32] tiles (16 KiB LDS — the
// occupancy sweet spot; every 32 KiB variant lost), global_load_lds w=16,
// 2x2 waves, 64x64 out/wave, BK=32, 2 barriers/K-step.
// NEW: XCD-aware block swizzle (NT%8==0 -> bijective): co-resident blocks on
// one XCD get a contiguous tile range -> shared A-panel in that XCD's L2.
// C/D layout: col = lane&15, row = (lane>>4)*4 + reg.
// ---------------------------------------------------------------------------
__global__ __launch_bounds__(256) void k_simmax(const bf16_t* __restrict__ xb,
                                                unsigned* __restrict__ row_max) {
    __shared__ bf16_t smA[128 * 32];
    __shared__ bf16_t smB[128 * 32];
    const int tid = threadIdx.x;
    const int w  = tid >> 6;
    const int l  = tid & 63;
    const int lr = l & 15;
    const int lk = (l >> 4) * 8;
    const int wr = w >> 1, wc = w & 1;

    // XCD swizzle: hardware block b (b%8 = XCD) -> tile t = (b%8)*(NT/8)+b/8
    const int t = (blockIdx.x & 7) * (NT / 8) + (blockIdx.x >> 3);

    // linear tile id -> upper-triangular (bi, bj), bi <= bj
    #define TOFF(b) ((b) * NB - ((b) * ((b) - 1)) / 2)
    int bi = (int)((float)(2 * NB + 1 -
                sqrtf((float)((2 * NB + 1) * (2 * NB + 1) - 8 * t))) * 0.5f);
    if (bi < 0) bi = 0;
    if (bi > NB - 1) bi = NB - 1;
    while (TOFF(bi + 1) <= t) ++bi;
    while (TOFF(bi) > t) --bi;
    const int bj = bi + (t - TOFF(bi));
    const int i0 = bi * 128, j0 = bj * 128;

    // staging: thread tid covers row tid>>2, 8-elem chunk tid&3 of a
    // row-major [128][32] tile (16B per lane); lands at wbase + lane*8 elems.
    const bf16_t* gA = xb + (size_t)(i0 + (tid >> 2)) * DIM + (tid & 3) * 8;
    const bf16_t* gB = xb + (size_t)(j0 + (tid >> 2)) * DIM + (tid & 3) * 8;
    const int wbase = (tid & ~63) * 8;      // wave-uniform LDS elem offset

    f32x4 acc[4][4] = {};
    const bf16_t* pa = smA + (wr * 64 + lr) * 32 + lk;
    const bf16_t* pb = smB + (wc * 64 + lr) * 32 + lk;

    for (int k = 0; k < DIM; k += 32) {
        GLOAD_LDS(gA + k,            smA + wbase);
        GLOAD_LDS(gA + 64 * DIM + k, smA + 2048 + wbase);
        GLOAD_LDS(gB + k,            smB + wbase);
        GLOAD_LDS(gB + 64 * DIM + k, smB + 2048 + wbase);
        __syncthreads();

        bf16x8 af[4], bfr[4];
        #pragma unroll
        for (int m = 0; m < 4; ++m) af[m]  = *(const bf16x8*)(pa + m * 512);
        #pragma unroll
        for (int n = 0; n < 4; ++n) bfr[n] = *(const bf16x8*)(pb + n * 512);
        #pragma unroll
        for (int m = 0; m < 4; ++m)
            #pragma unroll
            for (int n = 0; n < 4; ++n)
                acc[m][n] = __builtin_amdgcn_mfma_f32_16x16x32_bf16(
                                af[m], bfr[n], acc[m][n], 0, 0, 0);
        __syncthreads();
    }

    // Epilogue. Row-maxes for this wave's 64 rows (reduce over lr group).
    #pragma unroll
    for (int m = 0; m < 4; ++m) {
        #pragma unroll
        for (int j = 0; j < 4; ++j) {
            const int rowg = i0 + wr * 64 + m * 16 + (l >> 4) * 4 + j;
            float rm = -3.0e38f;
            #pragma unroll
            for (int n = 0; n < 4; ++n) {
                float s = acc[m][n][j];
                if (rowg == (j0 + wc * 64 + n * 16 + lr)) s = -3.0e38f;
                rm = fmaxf(rm, s);
            }
            #pragma unroll
            for (int mask = 1; mask < 16; mask <<= 1)
                rm = fmaxf(rm, __shfl_xor(rm, mask));
            if (lr == 0)
                atomicMax(&row_max[rowg], fmap(fminf(rm, 1.0f)));
        }
    }
    // Col-maxes feed the symmetric rows (off-diagonal blocks only).
    if (bi != bj) {
        #pragma unroll
        for (int n = 0; n < 4; ++n) {
            const int colg = j0 + wc * 64 + n * 16 + lr;
            float cm = -3.0e38f;
            #pragma unroll
            for (int m = 0; m < 4; ++m)
                #pragma unroll
                for (int j = 0; j < 4; ++j)
                    cm = fmaxf(cm, acc[m][n][j]);
            cm = fmaxf(cm, __shfl_xor(cm, 16));
            cm = fmaxf(cm, __shfl_xor(cm, 32));
            if (l < 16)
                atomicMax(&row_max[colg], fmap(fminf(cm, 1.0f)));
        }
    }
}

// ---------------------------------------------------------------------------
// Kernel 3: loss = -mean(log(sqrt(2 - 2*min(max_sim,1) + 1e-4) + 1e-8))
// ---------------------------------------------------------------------------
__global__ __launch_bounds__(1024) void k_finish(const unsigned* __restrict__ row_max,
                                                 float* __restrict__ out) {
    const int tid = threadIdx.x;
    float sum = 0.0f;
    #pragma unroll
    for (int i = tid; i < N_ROWS; i += 1024) {
        float sim = fminf(funmap(row_max[i]), 1.0f);
        float dist = sqrtf(2.0f - 2.0f * sim + 1e-4f);
        sum += logf(dist + 1e-8f);
    }
    #pragma unroll
    for (int m = 32; m >= 1; m >>= 1) sum += __shfl_xor(sum, m);
    __shared__ float wss[16];
    if ((tid & 63) == 0) wss[tid >> 6] = sum;
    __syncthreads();
    if (tid == 0) {
        float tot = 0.0f;
        #pragma unroll
        for (int i = 0; i < 16; ++i) tot += wss[i];
        out[0] = -tot / (float)N_ROWS;
    }
}

// ---------------------------------------------------------------------------
extern "C" void kernel_launch(void* const* d_in, const int* in_sizes, int n_in,
                              void* d_out, int out_size, void* d_ws, size_t ws_size,
                              hipStream_t stream) {
    const float* x = (const float*)d_in[0];
    bf16_t* xb = (bf16_t*)d_ws;                                   // 16 MiB
    unsigned* row_max = (unsigned*)((char*)d_ws +
                         (size_t)N_ROWS * DIM * sizeof(bf16_t));  // +32 KiB
    float* out = (float*)d_out;

    k_normalize<<<N_ROWS / 4, 256, 0, stream>>>(x, xb, row_max);
    k_simmax<<<NT, 256, 0, stream>>>(xb, row_max);
    k_finish<<<1, 1024, 0, stream>>>(row_max, out);
}

// Round 10
// 175.358 us; speedup vs baseline: 1.3685x; 1.0157x over previous
//
#include <hip/hip_runtime.h>
#include <hip/hip_bf16.h>
#include <math.h>

#define N_ROWS 8192
#define DIM    1024
#define NB     (N_ROWS / 128)       // 64 tiles per side
#define NT     (NB * (NB + 1) / 2)  // 2080 triangular blocks

typedef __bf16 bf16_t;
typedef __bf16 bf16x4 __attribute__((ext_vector_type(4)));
typedef __bf16 bf16x8 __attribute__((ext_vector_type(8)));
typedef float  f32x4  __attribute__((ext_vector_type(4)));

// global -> LDS direct copy, 16B per lane; LDS dest must be wave-uniform
#define GLOAD_LDS(g, s) __builtin_amdgcn_global_load_lds(                      \
    (const __attribute__((address_space(1))) void*)(g),                        \
    (__attribute__((address_space(3))) void*)(s), 16, 0, 0)

// Order-preserving float -> uint map (atomicMax on floats incl. negatives)
__device__ __forceinline__ unsigned fmap(float f) {
    unsigned u = __float_as_uint(f);
    return (u & 0x80000000u) ? ~u : (u | 0x80000000u);
}
__device__ __forceinline__ float funmap(unsigned u) {
    return (u & 0x80000000u) ? __uint_as_float(u ^ 0x80000000u)
                             : __uint_as_float(~u);
}

// ---------------------------------------------------------------------------
// Kernel 1: L2-normalize rows. One WAVE per row (no block reduce, no LDS).
// ---------------------------------------------------------------------------
__global__ __launch_bounds__(256) void k_normalize(const float* __restrict__ x,
                                                   bf16_t* __restrict__ xb,
                                                   unsigned* __restrict__ row_max) {
    const int tid = threadIdx.x;
    const int l   = tid & 63;
    const int row = blockIdx.x * 4 + (tid >> 6);
    const float4* xr = reinterpret_cast<const float4*>(x + (size_t)row * DIM);

    float4 v[4];
    float ss = 0.0f;
    #pragma unroll
    for (int c = 0; c < 4; ++c) {
        v[c] = xr[l + c * 64];
        ss += v[c].x * v[c].x + v[c].y * v[c].y + v[c].z * v[c].z + v[c].w * v[c].w;
    }
    #pragma unroll
    for (int m = 32; m >= 1; m >>= 1) ss += __shfl_xor(ss, m);
    const float scale = 1.0f / fmaxf(sqrtf(ss), 1e-12f);

    bf16x4* xo = reinterpret_cast<bf16x4*>(xb + (size_t)row * DIM);
    #pragma unroll
    for (int c = 0; c < 4; ++c) {
        bf16x4 o;
        o[0] = (bf16_t)(v[c].x * scale);
        o[1] = (bf16_t)(v[c].y * scale);
        o[2] = (bf16_t)(v[c].z * scale);
        o[3] = (bf16_t)(v[c].w * scale);
        xo[l + c * 64] = o;
    }

    if (blockIdx.x < N_ROWS / 256)
        row_max[blockIdx.x * 256 + tid] = 0u;   // mapped surrogate for -inf
}

// ---------------------------------------------------------------------------
// Kernel 2: row/col-max of sim = Xb*Xb^T over upper-triangular 128x128 tiles.
// Round-4 proven optimum: single-buffer [128][32] tiles (16 KiB LDS),
// global_load_lds w=16, 2x2 waves, 64x64 out/wave, BK=32, 2 barriers/K-step.
// No XCD swizzle (r8: FETCH down but dur up — not HBM-bound here).
// All pipelining variants (r5/r6/r7) regressed: occupancy + bank geometry
// beat source-level scheduling at this tile size (guide m99/m100/m131-141).
// C/D layout: col = lane&15, row = (lane>>4)*4 + reg.
// ---------------------------------------------------------------------------
__global__ __launch_bounds__(256) void k_simmax(const bf16_t* __restrict__ xb,
                                                unsigned* __restrict__ row_max) {
    __shared__ bf16_t smA[128 * 32];
    __shared__ bf16_t smB[128 * 32];
    const int tid = threadIdx.x;
    const int w  = tid >> 6;
    const int l  = tid & 63;
    const int lr = l & 15;
    const int lk = (l >> 4) * 8;
    const int wr = w >> 1, wc = w & 1;

    // linear block id -> upper-triangular (bi, bj), bi <= bj
    int t = blockIdx.x;
    #define TOFF(b) ((b) * NB - ((b) * ((b) - 1)) / 2)
    int bi = (int)((float)(2 * NB + 1 -
                sqrtf((float)((2 * NB + 1) * (2 * NB + 1) - 8 * t))) * 0.5f);
    if (bi < 0) bi = 0;
    if (bi > NB - 1) bi = NB - 1;
    while (TOFF(bi + 1) <= t) ++bi;
    while (TOFF(bi) > t) --bi;
    const int bj = bi + (t - TOFF(bi));
    const int i0 = bi * 128, j0 = bj * 128;

    // staging: thread tid covers row tid>>2, 8-elem chunk tid&3 of a
    // row-major [128][32] tile (16B per lane); lands at wbase + lane*8 elems.
    const bf16_t* gA = xb + (size_t)(i0 + (tid >> 2)) * DIM + (tid & 3) * 8;
    const bf16_t* gB = xb + (size_t)(j0 + (tid >> 2)) * DIM + (tid & 3) * 8;
    const int wbase = (tid & ~63) * 8;      // wave-uniform LDS elem offset

    f32x4 acc[4][4] = {};
    const bf16_t* pa = smA + (wr * 64 + lr) * 32 + lk;
    const bf16_t* pb = smB + (wc * 64 + lr) * 32 + lk;

    for (int k = 0; k < DIM; k += 32) {
        GLOAD_LDS(gA + k,            smA + wbase);
        GLOAD_LDS(gA + 64 * DIM + k, smA + 2048 + wbase);
        GLOAD_LDS(gB + k,            smB + wbase);
        GLOAD_LDS(gB + 64 * DIM + k, smB + 2048 + wbase);
        __syncthreads();

        bf16x8 af[4], bfr[4];
        #pragma unroll
        for (int m = 0; m < 4; ++m) af[m]  = *(const bf16x8*)(pa + m * 512);
        #pragma unroll
        for (int n = 0; n < 4; ++n) bfr[n] = *(const bf16x8*)(pb + n * 512);
        #pragma unroll
        for (int m = 0; m < 4; ++m)
            #pragma unroll
            for (int n = 0; n < 4; ++n)
                acc[m][n] = __builtin_amdgcn_mfma_f32_16x16x32_bf16(
                                af[m], bfr[n], acc[m][n], 0, 0, 0);
        __syncthreads();
    }

    // Epilogue. Row-maxes for this wave's 64 rows (reduce over lr group).
    #pragma unroll
    for (int m = 0; m < 4; ++m) {
        #pragma unroll
        for (int j = 0; j < 4; ++j) {
            const int rowg = i0 + wr * 64 + m * 16 + (l >> 4) * 4 + j;
            float rm = -3.0e38f;
            #pragma unroll
            for (int n = 0; n < 4; ++n) {
                float s = acc[m][n][j];
                if (rowg == (j0 + wc * 64 + n * 16 + lr)) s = -3.0e38f;
                rm = fmaxf(rm, s);
            }
            #pragma unroll
            for (int mask = 1; mask < 16; mask <<= 1)
                rm = fmaxf(rm, __shfl_xor(rm, mask));
            if (lr == 0)
                atomicMax(&row_max[rowg], fmap(fminf(rm, 1.0f)));
        }
    }
    // Col-maxes feed the symmetric rows (off-diagonal blocks only).
    if (bi != bj) {
        #pragma unroll
        for (int n = 0; n < 4; ++n) {
            const int colg = j0 + wc * 64 + n * 16 + lr;
            float cm = -3.0e38f;
            #pragma unroll
            for (int m = 0; m < 4; ++m)
                #pragma unroll
                for (int j = 0; j < 4; ++j)
                    cm = fmaxf(cm, acc[m][n][j]);
            cm = fmaxf(cm, __shfl_xor(cm, 16));
            cm = fmaxf(cm, __shfl_xor(cm, 32));
            if (l < 16)
                atomicMax(&row_max[colg], fmap(fminf(cm, 1.0f)));
        }
    }
}

// ---------------------------------------------------------------------------
// Kernel 3: loss = -mean(log(sqrt(2 - 2*min(max_sim,1) + 1e-4) + 1e-8))
// ---------------------------------------------------------------------------
__global__ __launch_bounds__(1024) void k_finish(const unsigned* __restrict__ row_max,
                                                 float* __restrict__ out) {
    const int tid = threadIdx.x;
    float sum = 0.0f;
    #pragma unroll
    for (int i = tid; i < N_ROWS; i += 1024) {
        float sim = fminf(funmap(row_max[i]), 1.0f);
        float dist = sqrtf(2.0f - 2.0f * sim + 1e-4f);
        sum += logf(dist + 1e-8f);
    }
    #pragma unroll
    for (int m = 32; m >= 1; m >>= 1) sum += __shfl_xor(sum, m);
    __shared__ float wss[16];
    if ((tid & 63) == 0) wss[tid >> 6] = sum;
    __syncthreads();
    if (tid == 0) {
        float tot = 0.0f;
        #pragma unroll
        for (int i = 0; i < 16; ++i) tot += wss[i];
        out[0] = -tot / (float)N_ROWS;
    }
}

// ---------------------------------------------------------------------------
extern "C" void kernel_launch(void* const* d_in, const int* in_sizes, int n_in,
                              void* d_out, int out_size, void* d_ws, size_t ws_size,
                              hipStream_t stream) {
    const float* x = (const float*)d_in[0];
    bf16_t* xb = (bf16_t*)d_ws;                                   // 16 MiB
    unsigned* row_max = (unsigned*)((char*)d_ws +
                         (size_t)N_ROWS * DIM * sizeof(bf16_t));  // +32 KiB
    float* out = (float*)d_out;

    k_normalize<<<N_ROWS / 4, 256, 0, stream>>>(x, xb, row_max);
    k_simmax<<<NT, 256, 0, stream>>>(xb, row_max);
    k_finish<<<1, 1024, 0, stream>>>(row_max, out);
}